// Round 8
// baseline (359.501 us; speedup 1.0000x reference)
//
#include <hip/hip_runtime.h>
#include <hip/hip_bf16.h>
#include <math.h>

#define B_   256
#define NPG_ 200
#define N0_  (B_*NPG_)     // 51200
#define DEGC 16
#define E_   (N0_*DEGC)    // 819200
#define SLOTG (NPG_*DEGC)  // 3200 edge slots per graph (original layout, never moved)
#define CSTRIDE 4096       // padded CSR slots per graph
#define CSRN (B_*CSTRIDE)
#define FIN_ 128
#define H_   256
#define K1_  100
#define K2_  50
#define K3_  25

// bijective XCD-chunk swizzle (m204)
__device__ __forceinline__ int xcd_swz(int bid, int nwg) {
    int q = nwg >> 3, r = nwg & 7;
    int x = bid & 7, j = bid >> 3;
    return (x < r ? x * (q + 1) : r * (q + 1) + (x - r) * q) + j;
}

__global__ void init_curmap_k(int* __restrict__ cm) {
    int i = blockIdx.x * 256 + threadIdx.x;
    if (i < N0_) cm[i] = i;
}

// ------- gemm_t: C[M x N] = A[M x K] @ W[K x N] (+bias/relu, + fused partial h.Ws dot) -------
// If Wsd != null: per 64-col tile writes partial dot to xsp[(bn>>6)*N0_ + row].
__global__ __launch_bounds__(256) void gemm_t(const float* __restrict__ A, const float* __restrict__ W,
                                              const float* __restrict__ bias, const float* __restrict__ Wsd,
                                              float* __restrict__ C, float* __restrict__ xsp,
                                              int M, int K, int N, int relu) {
    __shared__ float As[32][68];   // transposed: As[k][m]
    __shared__ float Bs[32][68];   // Bs[k][n]
    int t = threadIdx.x;
    int tx = t & 15, ty = t >> 4;
    int bm = xcd_swz(blockIdx.x, gridDim.x) * 64, bn = blockIdx.y * 64;
    int arow = t >> 2, akq = (t & 3) * 8;
    int brow = t >> 3, bnq = (t & 7) * 8;
    float acc[4][4] = {};
    for (int k0 = 0; k0 < K; k0 += 32) {
        float4 a0 = *(const float4*)&A[(size_t)(bm + arow) * K + k0 + akq];
        float4 a1 = *(const float4*)&A[(size_t)(bm + arow) * K + k0 + akq + 4];
        float4 b0 = *(const float4*)&W[(size_t)(k0 + brow) * N + bn + bnq];
        float4 b1 = *(const float4*)&W[(size_t)(k0 + brow) * N + bn + bnq + 4];
        As[akq + 0][arow] = a0.x; As[akq + 1][arow] = a0.y;
        As[akq + 2][arow] = a0.z; As[akq + 3][arow] = a0.w;
        As[akq + 4][arow] = a1.x; As[akq + 5][arow] = a1.y;
        As[akq + 6][arow] = a1.z; As[akq + 7][arow] = a1.w;
        *(float4*)&Bs[brow][bnq]     = b0;
        *(float4*)&Bs[brow][bnq + 4] = b1;
        __syncthreads();
        #pragma unroll
        for (int kk = 0; kk < 32; kk++) {
            float4 av = *(float4*)&As[kk][ty * 4];
            float4 bv = *(float4*)&Bs[kk][tx * 4];
            float a[4] = {av.x, av.y, av.z, av.w};
            float b[4] = {bv.x, bv.y, bv.z, bv.w};
            #pragma unroll
            for (int i = 0; i < 4; i++)
                #pragma unroll
                for (int j = 0; j < 4; j++) acc[i][j] += a[i] * b[j];
        }
        __syncthreads();
    }
    float bb[4] = {0.f, 0.f, 0.f, 0.f};
    if (bias) {
        #pragma unroll
        for (int j = 0; j < 4; j++) bb[j] = bias[bn + tx * 4 + j];
    }
    float wsv[4] = {0.f, 0.f, 0.f, 0.f};
    if (Wsd) {
        #pragma unroll
        for (int j = 0; j < 4; j++) wsv[j] = Wsd[bn + tx * 4 + j];
    }
    #pragma unroll
    for (int i = 0; i < 4; i++) {
        float4 c;
        c.x = acc[i][0] + bb[0]; c.y = acc[i][1] + bb[1];
        c.z = acc[i][2] + bb[2]; c.w = acc[i][3] + bb[3];
        if (relu) {
            c.x = fmaxf(c.x, 0.f); c.y = fmaxf(c.y, 0.f);
            c.z = fmaxf(c.z, 0.f); c.w = fmaxf(c.w, 0.f);
        }
        *(float4*)&C[(size_t)(bm + ty * 4 + i) * N + bn + tx * 4] = c;
        if (Wsd) {
            float p = c.x * wsv[0] + c.y * wsv[1] + c.z * wsv[2] + c.w * wsv[3];
            p += __shfl_xor(p, 1); p += __shfl_xor(p, 2);
            p += __shfl_xor(p, 4); p += __shfl_xor(p, 8);
            if (tx == 0) xsp[(size_t)(bn >> 6) * N0_ + bm + ty * 4 + i] = p;
        }
    }
}

// -------- per-graph CSR build via CURMAP (edges never rewritten) --------
__global__ void csr_build_k(const int* __restrict__ esrc, const int* __restrict__ edst,
                            const int* __restrict__ curmap, int* __restrict__ offs,
                            int* __restrict__ offe, int* __restrict__ csrc,
                            float* __restrict__ coef, float* __restrict__ dinv, int npg) {
    __shared__ int   cml[256];
    __shared__ int   cnt[256];
    __shared__ int   sc[256];
    __shared__ int   pos[256];
    __shared__ float dv[256];
    __shared__ int   ecache[SLOTG];
    int g = xcd_swz(blockIdx.x, B_);
    int t = threadIdx.x;
    int ebase = g * SLOTG;
    int ob0 = g * NPG_;
    int nb0 = g * npg;
    int cbase = g * CSTRIDE;
    cml[t] = (t < NPG_) ? curmap[ob0 + t] : -1;
    cnt[t] = 0;
    __syncthreads();
    for (int e = t; e < SLOTG; e += 256) {
        int cs = cml[esrc[ebase + e] - ob0];
        int cd = cml[edst[ebase + e] - ob0];
        int pk = -1;
        if (cs >= 0 && cd >= 0) {
            int cs_l = cs - nb0, cd_l = cd - nb0;
            pk = cs_l | (cd_l << 8);
            atomicAdd(&cnt[cd_l], 1);
        }
        ecache[e] = pk;
    }
    __syncthreads();
    int v = (t < npg) ? cnt[t] : 0;
    float dloc = rsqrtf((float)v + 1.0f);
    dv[t] = dloc;
    int vp = (v + 3) & ~3;
    sc[t] = vp; __syncthreads();
    for (int d = 1; d < 256; d <<= 1) {
        int u = (t >= d) ? sc[t - d] : 0;
        __syncthreads();
        sc[t] += u;
        __syncthreads();
    }
    int excl = sc[t] - vp;
    pos[t] = cbase + excl;
    if (t < npg) {
        offs[nb0 + t] = cbase + excl;
        offe[nb0 + t] = cbase + excl + vp;
        dinv[nb0 + t] = dloc;
        for (int p = v; p < vp; p++) {
            csrc[cbase + excl + p] = nb0 + t;
            coef[cbase + excl + p] = 0.0f;
        }
    }
    __syncthreads();
    for (int e = t; e < SLOTG; e += 256) {
        int pk = ecache[e];
        if (pk >= 0) {
            int cs_l = pk & 255, cd_l = pk >> 8;
            int p = atomicAdd(&pos[cd_l], 1);
            csrc[p] = nb0 + cs_l;
            coef[p] = dv[cd_l] * dv[cs_l];
        }
    }
}

// ------- LDS-staged pure aggregation: AX = D^-1/2(A+I)D^-1/2 . X -------
// One block per (graph, 64-feature part). LDS = npg*64 floats (<= 50 KB).
__global__ __launch_bounds__(512) void agg_lds_k(
        const float* __restrict__ X, const int* __restrict__ offs,
        const int* __restrict__ offe, const int* __restrict__ csrc,
        const float* __restrict__ coef, const float* __restrict__ dinv,
        float* __restrict__ AX, int npg, int FI, int parts) {
    extern __shared__ float lds[];
    int gid = xcd_swz(blockIdx.x, gridDim.x);
    int g = gid / parts, part = gid - g * parts;
    int f0 = part * 64;
    int nb0 = g * npg;
    int t = threadIdx.x;
    int total4 = npg * 16;
    for (int i = t; i < total4; i += 512) {
        int row = i >> 4, c4 = i & 15;
        ((float4*)lds)[i] = *(const float4*)&X[(size_t)(nb0 + row) * FI + f0 + (c4 << 2)];
    }
    __syncthreads();
    int wid = t >> 6, lane = t & 63;
    for (int nl = wid; nl < npg; nl += 8) {
        int node = nb0 + nl;
        float dd = dinv[node];
        int e0 = offs[node], e1 = offe[node];
        float a = 0.f;
        for (int j = e0; j < e1; j += 4) {
            int4   s4 = *(const int4*)&csrc[j];
            float4 c4 = *(const float4*)&coef[j];
            a += c4.x * lds[((s4.x - nb0) << 6) | lane]
               + c4.y * lds[((s4.y - nb0) << 6) | lane]
               + c4.z * lds[((s4.z - nb0) << 6) | lane]
               + c4.w * lds[((s4.w - nb0) << 6) | lane];
        }
        a += dd * dd * lds[(nl << 6) | lane];
        AX[(size_t)node * FI + f0 + lane] = a;
    }
}

// -------- fused score GCN + top-k + pool + readout + CURMAP compose --------
__global__ void score_topk_pool_k(const float* __restrict__ h, const float* __restrict__ xsp,
                                  const int* __restrict__ offs, const int* __restrict__ offe,
                                  const int* __restrict__ csrc, const float* __restrict__ coef,
                                  const float* __restrict__ dinv, const float* __restrict__ bs,
                                  int* __restrict__ curmap, float* __restrict__ ph,
                                  float* __restrict__ z, int npg, int k, int accumulate) {
    __shared__ float xsl[256];
    __shared__ float sc[256];
    __shared__ int   id[256];
    __shared__ int   rl[256];
    __shared__ int   ps[128];
    __shared__ float ts[128];
    int g = xcd_swz(blockIdx.x, B_);
    int t = threadIdx.x;
    int nb0 = g * npg;
    float xv = 0.f;
    if (t < npg) {
        int gi = nb0 + t;
        xv = xsp[gi] + xsp[N0_ + gi] + xsp[2 * N0_ + gi] + xsp[3 * N0_ + gi];
    }
    xsl[t] = xv;
    rl[t] = -1;
    __syncthreads();
    float scv = -INFINITY;
    if (t < npg) {
        int gi = nb0 + t;
        float dd = dinv[gi];
        float acc = 0.f;
        for (int j = offs[gi]; j < offe[gi]; j++)
            acc += coef[j] * xsl[csrc[j] - nb0];
        scv = acc + xsl[t] * dd * dd + bs[0];
    }
    sc[t] = scv;
    id[t] = (t < npg) ? t : 0x7fffffff;
    __syncthreads();
    for (int ksz = 2; ksz <= 256; ksz <<= 1) {
        for (int j = ksz >> 1; j > 0; j >>= 1) {
            int ixj = t ^ j;
            if (ixj > t) {
                float s1 = sc[t], s2 = sc[ixj];
                int i1 = id[t], i2 = id[ixj];
                bool asc = ((t & ksz) == 0);
                bool agtb = (s1 < s2) || (s1 == s2 && i1 > i2);
                if (asc ? agtb : !agtb) { sc[t] = s2; sc[ixj] = s1; id[t] = i2; id[ixj] = i1; }
            }
            __syncthreads();
        }
    }
    if (t < k) {
        rl[id[t]] = g * k + t;
        ps[t] = nb0 + id[t];
        ts[t] = tanhf(sc[t]);
    }
    __syncthreads();
    if (t < NPG_) {
        int o = g * NPG_ + t;
        int old = curmap[o];
        curmap[o] = (old < 0) ? -1 : rl[old - nb0];
    }
    float mx = -INFINITY, sm = 0.f;
    for (int j = 0; j < k; j++) {
        float v = h[(size_t)ps[j] * H_ + t] * ts[j];
        ph[(size_t)(g * k + j) * H_ + t] = v;
        mx = fmaxf(mx, v); sm += v;
    }
    float mean = sm / (float)k;
    if (accumulate) { z[g * 512 + t] += mx; z[g * 512 + 256 + t] += mean; }
    else            { z[g * 512 + t]  = mx; z[g * 512 + 256 + t]  = mean; }
}

// ---------------- fused MLP layer-3 + log_softmax ----------------
__global__ void mlp3_lsm_k(const float* __restrict__ A, const float* __restrict__ W,
                           const float* __restrict__ bias, float* __restrict__ out) {
    int m = blockIdx.x, l = threadIdx.x;
    float a0 = A[m * 128 + l], a1 = A[m * 128 + 64 + l];
    float r[10];
    #pragma unroll
    for (int n = 0; n < 10; n++) r[n] = a0 * W[l * 10 + n] + a1 * W[(l + 64) * 10 + n];
    #pragma unroll
    for (int d = 1; d < 64; d <<= 1)
        #pragma unroll
        for (int n = 0; n < 10; n++) r[n] += __shfl_xor(r[n], d);
    float v[10]; float mx = -INFINITY;
    #pragma unroll
    for (int n = 0; n < 10; n++) { v[n] = r[n] + bias[n]; mx = fmaxf(mx, v[n]); }
    float s = 0.f;
    #pragma unroll
    for (int n = 0; n < 10; n++) s += expf(v[n] - mx);
    float ls = logf(s);
    if (l < 10) out[m * 10 + l] = v[l] - mx - ls;
}

extern "C" void kernel_launch(void* const* d_in, const int* in_sizes, int n_in,
                              void* d_out, int out_size, void* d_ws, size_t ws_size,
                              hipStream_t stream) {
    const float* x   = (const float*)d_in[0];
    const int*  esrc = (const int*) d_in[1];
    const int*  edst = (const int*) d_in[2];
    const float *W1 = (const float*)d_in[3],  *b1 = (const float*)d_in[4];
    const float *Ws1= (const float*)d_in[5],  *bs1= (const float*)d_in[6];
    const float *W2 = (const float*)d_in[7],  *b2 = (const float*)d_in[8];
    const float *Ws2= (const float*)d_in[9],  *bs2= (const float*)d_in[10];
    const float *W3 = (const float*)d_in[11], *b3 = (const float*)d_in[12];
    const float *Ws3= (const float*)d_in[13], *bs3= (const float*)d_in[14];
    const float *Wl1= (const float*)d_in[15], *bl1= (const float*)d_in[16];
    const float *Wl2= (const float*)d_in[17], *bl2= (const float*)d_in[18];
    const float *Wl3= (const float*)d_in[19], *bl3= (const float*)d_in[20];
    float* out = (float*)d_out;

    // ---- workspace layout ----
    float* ws = (float*)d_ws;
    float* AX    = ws;                         // N0*H (aggregated input, reused)
    float* Hb    = AX + (size_t)N0_ * H_;      // N0*H
    float* PH    = Hb + (size_t)N0_ * H_;      // (B*K1)*H
    float* DINV  = PH + (size_t)B_ * K1_ * H_; // N0
    float* XSP   = DINV + N0_;                 // 4*N0 (partial h.Ws dots)
    int*   CURMAP= (int*)(XSP + 4 * N0_);      // N0
    int*   OFFS  = CURMAP + N0_;               // N0
    int*   OFFE  = OFFS + N0_;                 // N0
    int*   CSRC  = OFFE + N0_;                 // CSRN
    float* COEF  = (float*)(CSRC + CSRN);      // CSRN
    float* Z     = COEF + CSRN;                // B*512
    float* Z1    = Z + B_ * 512;               // B*256
    float* Z2    = Z1 + B_ * 256;              // B*128

    init_curmap_k<<<N0_ / 256, 256, 0, stream>>>(CURMAP);

    const int npgs[3]  = { NPG_, K1_, K2_ };
    const int ks[3]    = { K1_, K2_, K3_ };
    const int fis[3]   = { FIN_, H_, H_ };
    const float* Xm[3]  = { x, PH, PH };
    const float* Wm[3]  = { W1, W2, W3 };
    const float* bm[3]  = { b1, b2, b3 };
    const float* Wsm[3] = { Ws1, Ws2, Ws3 };
    const float* bsm[3] = { bs1, bs2, bs3 };

    for (int st = 0; st < 3; st++) {
        int npg = npgs[st], k = ks[st], FI = fis[st];
        int n = B_ * npg;
        int parts = FI / 64;

        // 1. per-graph padded CSR build from original edges + CURMAP
        csr_build_k<<<B_, 256, 0, stream>>>(esrc, edst, CURMAP, OFFS, OFFE, CSRC, COEF, DINV, npg);

        // 2. AX = Agg(X) — LDS-staged, 64-feature parts (aggregate-first)
        agg_lds_k<<<parts * B_, 512, npg * 64 * 4, stream>>>(
            Xm[st], OFFS, OFFE, CSRC, COEF, DINV, AX, npg, FI, parts);

        // 3. h = relu(AX @ W + b), fused partial xs = h.Ws per 64-col tile
        gemm_t<<<dim3(n / 64, H_ / 64), 256, 0, stream>>>(
            AX, Wm[st], bm[st], Wsm[st], Hb, XSP, n, FI, H_, 1);

        // 4-7. score GCN + top-k + pool + readout + CURMAP compose
        score_topk_pool_k<<<B_, 256, 0, stream>>>(Hb, XSP, OFFS, OFFE, CSRC, COEF, DINV, bsm[st],
                                                  CURMAP, PH, Z, npg, k, st > 0 ? 1 : 0);
    }

    // ---- MLP head ----
    gemm_t<<<dim3(B_ / 64, 256 / 64), 256, 0, stream>>>(Z,  Wl1, bl1, nullptr, Z1, nullptr, B_, 512, 256, 1);
    gemm_t<<<dim3(B_ / 64, 128 / 64), 256, 0, stream>>>(Z1, Wl2, bl2, nullptr, Z2, nullptr, B_, 256, 128, 1);
    mlp3_lsm_k<<<B_, 64, 0, stream>>>(Z2, Wl3, bl3, out);
}

// Round 9
// 286.832 us; speedup vs baseline: 1.2533x; 1.2533x over previous
//
#include <hip/hip_runtime.h>
#include <hip/hip_bf16.h>
#include <math.h>

typedef __hip_bfloat16 bf16;
typedef __attribute__((ext_vector_type(8))) short bf16x8;
typedef __attribute__((ext_vector_type(4))) float f32x4;

#define B_   256
#define NPG_ 200
#define N0_  (B_*NPG_)     // 51200
#define DEGC 16
#define E_   (N0_*DEGC)    // 819200
#define SLOTG (NPG_*DEGC)  // 3200 edge slots per graph (original layout, never moved)
#define CSTRIDE 4096       // padded CSR slots per graph
#define CSRN (B_*CSTRIDE)
#define FIN_ 128
#define H_   256
#define K1_  100
#define K2_  50
#define K3_  25

// bijective XCD-chunk swizzle (m204)
__device__ __forceinline__ int xcd_swz(int bid, int nwg) {
    int q = nwg >> 3, r = nwg & 7;
    int x = bid & 7, j = bid >> 3;
    return (x < r ? x * (q + 1) : r * (q + 1) + (x - r) * q) + j;
}

__global__ void init_curmap_k(int* __restrict__ cm) {
    int i = blockIdx.x * 256 + threadIdx.x;
    if (i < N0_) cm[i] = i;
}

// ---- W convert: W[K][N] f32 -> WT hi/lo bf16 [N][K] (transpose + split) ----
__global__ void wconv_k(const float* __restrict__ W, bf16* __restrict__ TH,
                        bf16* __restrict__ TL, int K, int N) {
    __shared__ float tile[32][33];
    int k0 = blockIdx.x * 32, n0 = blockIdx.y * 32;
    int t = threadIdx.x;
    int tc = t & 31, tr = t >> 5;
    #pragma unroll
    for (int i = 0; i < 4; i++) {
        int kk = tr + i * 8;
        tile[kk][tc] = W[(size_t)(k0 + kk) * N + n0 + tc];
    }
    __syncthreads();
    #pragma unroll
    for (int i = 0; i < 4; i++) {
        int nn = tr + i * 8;
        float v = tile[tc][nn];
        bf16 h = __float2bfloat16(v);
        TH[(size_t)(n0 + nn) * K + k0 + tc] = h;
        TL[(size_t)(n0 + nn) * K + k0 + tc] = __float2bfloat16(v - __bfloat162float(h));
    }
}

// ---- MFMA split-bf16 GEMM: C[M][N] = relu(A@W + bias), fused partial h.Ws dots ----
// A as AH/AL bf16 [M][K]; W as BTH/BTL bf16 [N][K] (pre-transposed).
// Block 64x128 (4 waves, each 32x64), K-step 32.
__global__ __launch_bounds__(256) void gemm_mfma(
        const bf16* __restrict__ AH, const bf16* __restrict__ AL,
        const bf16* __restrict__ BTH, const bf16* __restrict__ BTL,
        const float* __restrict__ bias, const float* __restrict__ Wsd,
        float* __restrict__ C, float* __restrict__ xsp, int M, int K, int N) {
    __shared__ bf16 lAh[64 * 40], lAl[64 * 40];
    __shared__ bf16 lBh[128 * 40], lBl[128 * 40];
    int t = threadIdx.x;
    int w = t >> 6, l = t & 63;
    int wr = w >> 1, wc = w & 1;
    int bm = xcd_swz(blockIdx.x, gridDim.x) * 64;
    int bn = blockIdx.y * 128;
    int srow = t >> 2, skg = (t & 3) * 8;
    f32x4 acc[2][4] = {};
    int coll = l & 15, kg8 = (l >> 4) * 8;
    for (int k0 = 0; k0 < K; k0 += 32) {
        *(uint4*)&lAh[srow * 40 + skg] = *(const uint4*)&AH[(size_t)(bm + srow) * K + k0 + skg];
        *(uint4*)&lAl[srow * 40 + skg] = *(const uint4*)&AL[(size_t)(bm + srow) * K + k0 + skg];
        *(uint4*)&lBh[srow * 40 + skg]        = *(const uint4*)&BTH[(size_t)(bn + srow) * K + k0 + skg];
        *(uint4*)&lBh[(64 + srow) * 40 + skg] = *(const uint4*)&BTH[(size_t)(bn + 64 + srow) * K + k0 + skg];
        *(uint4*)&lBl[srow * 40 + skg]        = *(const uint4*)&BTL[(size_t)(bn + srow) * K + k0 + skg];
        *(uint4*)&lBl[(64 + srow) * 40 + skg] = *(const uint4*)&BTL[(size_t)(bn + 64 + srow) * K + k0 + skg];
        __syncthreads();
        bf16x8 ah[2], al[2], bh[4], bl[4];
        #pragma unroll
        for (int rt = 0; rt < 2; rt++) {
            int row = wr * 32 + rt * 16 + coll;
            ah[rt] = *(const bf16x8*)&lAh[row * 40 + kg8];
            al[rt] = *(const bf16x8*)&lAl[row * 40 + kg8];
        }
        #pragma unroll
        for (int ct = 0; ct < 4; ct++) {
            int col = wc * 64 + ct * 16 + coll;
            bh[ct] = *(const bf16x8*)&lBh[col * 40 + kg8];
            bl[ct] = *(const bf16x8*)&lBl[col * 40 + kg8];
        }
        #pragma unroll
        for (int rt = 0; rt < 2; rt++)
            #pragma unroll
            for (int ct = 0; ct < 4; ct++) {
                acc[rt][ct] = __builtin_amdgcn_mfma_f32_16x16x32_bf16(ah[rt], bh[ct], acc[rt][ct], 0, 0, 0);
                acc[rt][ct] = __builtin_amdgcn_mfma_f32_16x16x32_bf16(ah[rt], bl[ct], acc[rt][ct], 0, 0, 0);
                acc[rt][ct] = __builtin_amdgcn_mfma_f32_16x16x32_bf16(al[rt], bh[ct], acc[rt][ct], 0, 0, 0);
            }
        __syncthreads();
    }
    // epilogue: bias + relu + store + fused score partial dot
    int gq = l >> 4;
    float bb[4], wv[4];
    #pragma unroll
    for (int ct = 0; ct < 4; ct++) {
        int col = bn + wc * 64 + ct * 16 + coll;
        bb[ct] = bias[col];
        wv[ct] = Wsd ? Wsd[col] : 0.f;
    }
    #pragma unroll
    for (int rt = 0; rt < 2; rt++) {
        int rowb = bm + wr * 32 + rt * 16 + gq * 4;
        float pr[4] = {0.f, 0.f, 0.f, 0.f};
        #pragma unroll
        for (int ct = 0; ct < 4; ct++) {
            int col = bn + wc * 64 + ct * 16 + coll;
            #pragma unroll
            for (int r = 0; r < 4; r++) {
                float v = fmaxf(acc[rt][ct][r] + bb[ct], 0.f);
                C[(size_t)(rowb + r) * N + col] = v;
                pr[r] += v * wv[ct];
            }
        }
        if (Wsd) {
            #pragma unroll
            for (int r = 0; r < 4; r++) {
                pr[r] += __shfl_xor(pr[r], 1); pr[r] += __shfl_xor(pr[r], 2);
                pr[r] += __shfl_xor(pr[r], 4); pr[r] += __shfl_xor(pr[r], 8);
            }
            if (coll == 0) {
                int part = (bn >> 6) + wc;
                #pragma unroll
                for (int r = 0; r < 4; r++)
                    xsp[(size_t)part * N0_ + rowb + r] = pr[r];
            }
        }
    }
}

// ---------------- gemm_t (f32) for the small MLP layers ----------------
__global__ __launch_bounds__(256) void gemm_t(const float* __restrict__ A, const float* __restrict__ W,
                                              const float* __restrict__ bias, float* __restrict__ C,
                                              int M, int K, int N, int relu) {
    __shared__ float As[32][68];
    __shared__ float Bs[32][68];
    int t = threadIdx.x;
    int tx = t & 15, ty = t >> 4;
    int bm = xcd_swz(blockIdx.x, gridDim.x) * 64, bn = blockIdx.y * 64;
    int arow = t >> 2, akq = (t & 3) * 8;
    int brow = t >> 3, bnq = (t & 7) * 8;
    float acc[4][4] = {};
    for (int k0 = 0; k0 < K; k0 += 32) {
        float4 a0 = *(const float4*)&A[(size_t)(bm + arow) * K + k0 + akq];
        float4 a1 = *(const float4*)&A[(size_t)(bm + arow) * K + k0 + akq + 4];
        float4 b0 = *(const float4*)&W[(size_t)(k0 + brow) * N + bn + bnq];
        float4 b1 = *(const float4*)&W[(size_t)(k0 + brow) * N + bn + bnq + 4];
        As[akq + 0][arow] = a0.x; As[akq + 1][arow] = a0.y;
        As[akq + 2][arow] = a0.z; As[akq + 3][arow] = a0.w;
        As[akq + 4][arow] = a1.x; As[akq + 5][arow] = a1.y;
        As[akq + 6][arow] = a1.z; As[akq + 7][arow] = a1.w;
        *(float4*)&Bs[brow][bnq]     = b0;
        *(float4*)&Bs[brow][bnq + 4] = b1;
        __syncthreads();
        #pragma unroll
        for (int kk = 0; kk < 32; kk++) {
            float4 av = *(float4*)&As[kk][ty * 4];
            float4 bv = *(float4*)&Bs[kk][tx * 4];
            float a[4] = {av.x, av.y, av.z, av.w};
            float b[4] = {bv.x, bv.y, bv.z, bv.w};
            #pragma unroll
            for (int i = 0; i < 4; i++)
                #pragma unroll
                for (int j = 0; j < 4; j++) acc[i][j] += a[i] * b[j];
        }
        __syncthreads();
    }
    float bb[4];
    #pragma unroll
    for (int j = 0; j < 4; j++) bb[j] = bias[bn + tx * 4 + j];
    #pragma unroll
    for (int i = 0; i < 4; i++) {
        float4 c;
        c.x = acc[i][0] + bb[0]; c.y = acc[i][1] + bb[1];
        c.z = acc[i][2] + bb[2]; c.w = acc[i][3] + bb[3];
        if (relu) {
            c.x = fmaxf(c.x, 0.f); c.y = fmaxf(c.y, 0.f);
            c.z = fmaxf(c.z, 0.f); c.w = fmaxf(c.w, 0.f);
        }
        *(float4*)&C[(size_t)(bm + ty * 4 + i) * N + bn + tx * 4] = c;
    }
}

// -------- per-graph CSR build via CURMAP (edges never rewritten) --------
__global__ void csr_build_k(const int* __restrict__ esrc, const int* __restrict__ edst,
                            const int* __restrict__ curmap, int* __restrict__ offs,
                            int* __restrict__ offe, int* __restrict__ csrc,
                            float* __restrict__ coef, float* __restrict__ dinv, int npg) {
    __shared__ int   cml[256];
    __shared__ int   cnt[256];
    __shared__ int   sc[256];
    __shared__ int   pos[256];
    __shared__ float dv[256];
    __shared__ int   ecache[SLOTG];
    int g = xcd_swz(blockIdx.x, B_);
    int t = threadIdx.x;
    int ebase = g * SLOTG;
    int ob0 = g * NPG_;
    int nb0 = g * npg;
    int cbase = g * CSTRIDE;
    cml[t] = (t < NPG_) ? curmap[ob0 + t] : -1;
    cnt[t] = 0;
    __syncthreads();
    for (int e = t; e < SLOTG; e += 256) {
        int cs = cml[esrc[ebase + e] - ob0];
        int cd = cml[edst[ebase + e] - ob0];
        int pk = -1;
        if (cs >= 0 && cd >= 0) {
            int cs_l = cs - nb0, cd_l = cd - nb0;
            pk = cs_l | (cd_l << 8);
            atomicAdd(&cnt[cd_l], 1);
        }
        ecache[e] = pk;
    }
    __syncthreads();
    int v = (t < npg) ? cnt[t] : 0;
    float dloc = rsqrtf((float)v + 1.0f);
    dv[t] = dloc;
    int vp = (v + 3) & ~3;
    sc[t] = vp; __syncthreads();
    for (int d = 1; d < 256; d <<= 1) {
        int u = (t >= d) ? sc[t - d] : 0;
        __syncthreads();
        sc[t] += u;
        __syncthreads();
    }
    int excl = sc[t] - vp;
    pos[t] = cbase + excl;
    if (t < npg) {
        offs[nb0 + t] = cbase + excl;
        offe[nb0 + t] = cbase + excl + vp;
        dinv[nb0 + t] = dloc;
        for (int p = v; p < vp; p++) {
            csrc[cbase + excl + p] = nb0 + t;
            coef[cbase + excl + p] = 0.0f;
        }
    }
    __syncthreads();
    for (int e = t; e < SLOTG; e += 256) {
        int pk = ecache[e];
        if (pk >= 0) {
            int cs_l = pk & 255, cd_l = pk >> 8;
            int p = atomicAdd(&pos[cd_l], 1);
            csrc[p] = nb0 + cs_l;
            coef[p] = dv[cd_l] * dv[cs_l];
        }
    }
}

// ------- LDS-staged aggregation: AX = D^-1/2(A+I)D^-1/2 . X, output split bf16 -------
__global__ __launch_bounds__(512) void agg_lds_k(
        const float* __restrict__ X, const int* __restrict__ offs,
        const int* __restrict__ offe, const int* __restrict__ csrc,
        const float* __restrict__ coef, const float* __restrict__ dinv,
        bf16* __restrict__ AHo, bf16* __restrict__ ALo, int npg, int FI, int parts) {
    extern __shared__ float lds[];
    int gid = xcd_swz(blockIdx.x, gridDim.x);
    int g = gid / parts, part = gid - g * parts;
    int f0 = part * 64;
    int nb0 = g * npg;
    int t = threadIdx.x;
    int total4 = npg * 16;
    for (int i = t; i < total4; i += 512) {
        int row = i >> 4, c4 = i & 15;
        ((float4*)lds)[i] = *(const float4*)&X[(size_t)(nb0 + row) * FI + f0 + (c4 << 2)];
    }
    __syncthreads();
    int wid = t >> 6, lane = t & 63;
    for (int nl = wid; nl < npg; nl += 8) {
        int node = nb0 + nl;
        float dd = dinv[node];
        int e0 = offs[node], e1 = offe[node];
        float a = 0.f;
        for (int j = e0; j < e1; j += 4) {
            int4   s4 = *(const int4*)&csrc[j];
            float4 c4 = *(const float4*)&coef[j];
            a += c4.x * lds[((s4.x - nb0) << 6) | lane]
               + c4.y * lds[((s4.y - nb0) << 6) | lane]
               + c4.z * lds[((s4.z - nb0) << 6) | lane]
               + c4.w * lds[((s4.w - nb0) << 6) | lane];
        }
        a += dd * dd * lds[(nl << 6) | lane];
        bf16 hh = __float2bfloat16(a);
        AHo[(size_t)node * FI + f0 + lane] = hh;
        ALo[(size_t)node * FI + f0 + lane] = __float2bfloat16(a - __bfloat162float(hh));
    }
}

// -------- fused score GCN + top-k + pool + readout + CURMAP compose --------
__global__ void score_topk_pool_k(const float* __restrict__ h, const float* __restrict__ xsp,
                                  const int* __restrict__ offs, const int* __restrict__ offe,
                                  const int* __restrict__ csrc, const float* __restrict__ coef,
                                  const float* __restrict__ dinv, const float* __restrict__ bs,
                                  int* __restrict__ curmap, float* __restrict__ ph,
                                  float* __restrict__ z, int npg, int k, int accumulate) {
    __shared__ float xsl[256];
    __shared__ float sc[256];
    __shared__ int   id[256];
    __shared__ int   rl[256];
    __shared__ int   ps[128];
    __shared__ float ts[128];
    int g = xcd_swz(blockIdx.x, B_);
    int t = threadIdx.x;
    int nb0 = g * npg;
    float xv = 0.f;
    if (t < npg) {
        int gi = nb0 + t;
        xv = xsp[gi] + xsp[N0_ + gi] + xsp[2 * N0_ + gi] + xsp[3 * N0_ + gi];
    }
    xsl[t] = xv;
    rl[t] = -1;
    __syncthreads();
    float scv = -INFINITY;
    if (t < npg) {
        int gi = nb0 + t;
        float dd = dinv[gi];
        float acc = 0.f;
        for (int j = offs[gi]; j < offe[gi]; j++)
            acc += coef[j] * xsl[csrc[j] - nb0];
        scv = acc + xsl[t] * dd * dd + bs[0];
    }
    sc[t] = scv;
    id[t] = (t < npg) ? t : 0x7fffffff;
    __syncthreads();
    for (int ksz = 2; ksz <= 256; ksz <<= 1) {
        for (int j = ksz >> 1; j > 0; j >>= 1) {
            int ixj = t ^ j;
            if (ixj > t) {
                float s1 = sc[t], s2 = sc[ixj];
                int i1 = id[t], i2 = id[ixj];
                bool asc = ((t & ksz) == 0);
                bool agtb = (s1 < s2) || (s1 == s2 && i1 > i2);
                if (asc ? agtb : !agtb) { sc[t] = s2; sc[ixj] = s1; id[t] = i2; id[ixj] = i1; }
            }
            __syncthreads();
        }
    }
    if (t < k) {
        rl[id[t]] = g * k + t;
        ps[t] = nb0 + id[t];
        ts[t] = tanhf(sc[t]);
    }
    __syncthreads();
    if (t < NPG_) {
        int o = g * NPG_ + t;
        int old = curmap[o];
        curmap[o] = (old < 0) ? -1 : rl[old - nb0];
    }
    float mx = -INFINITY, sm = 0.f;
    for (int j = 0; j < k; j++) {
        float v = h[(size_t)ps[j] * H_ + t] * ts[j];
        ph[(size_t)(g * k + j) * H_ + t] = v;
        mx = fmaxf(mx, v); sm += v;
    }
    float mean = sm / (float)k;
    if (accumulate) { z[g * 512 + t] += mx; z[g * 512 + 256 + t] += mean; }
    else            { z[g * 512 + t]  = mx; z[g * 512 + 256 + t]  = mean; }
}

// ---------------- fused MLP layer-3 + log_softmax ----------------
__global__ void mlp3_lsm_k(const float* __restrict__ A, const float* __restrict__ W,
                           const float* __restrict__ bias, float* __restrict__ out) {
    int m = blockIdx.x, l = threadIdx.x;
    float a0 = A[m * 128 + l], a1 = A[m * 128 + 64 + l];
    float r[10];
    #pragma unroll
    for (int n = 0; n < 10; n++) r[n] = a0 * W[l * 10 + n] + a1 * W[(l + 64) * 10 + n];
    #pragma unroll
    for (int d = 1; d < 64; d <<= 1)
        #pragma unroll
        for (int n = 0; n < 10; n++) r[n] += __shfl_xor(r[n], d);
    float v[10]; float mx = -INFINITY;
    #pragma unroll
    for (int n = 0; n < 10; n++) { v[n] = r[n] + bias[n]; mx = fmaxf(mx, v[n]); }
    float s = 0.f;
    #pragma unroll
    for (int n = 0; n < 10; n++) s += expf(v[n] - mx);
    float ls = logf(s);
    if (l < 10) out[m * 10 + l] = v[l] - mx - ls;
}

extern "C" void kernel_launch(void* const* d_in, const int* in_sizes, int n_in,
                              void* d_out, int out_size, void* d_ws, size_t ws_size,
                              hipStream_t stream) {
    const float* x   = (const float*)d_in[0];
    const int*  esrc = (const int*) d_in[1];
    const int*  edst = (const int*) d_in[2];
    const float *W1 = (const float*)d_in[3],  *b1 = (const float*)d_in[4];
    const float *Ws1= (const float*)d_in[5],  *bs1= (const float*)d_in[6];
    const float *W2 = (const float*)d_in[7],  *b2 = (const float*)d_in[8];
    const float *Ws2= (const float*)d_in[9],  *bs2= (const float*)d_in[10];
    const float *W3 = (const float*)d_in[11], *b3 = (const float*)d_in[12];
    const float *Ws3= (const float*)d_in[13], *bs3= (const float*)d_in[14];
    const float *Wl1= (const float*)d_in[15], *bl1= (const float*)d_in[16];
    const float *Wl2= (const float*)d_in[17], *bl2= (const float*)d_in[18];
    const float *Wl3= (const float*)d_in[19], *bl3= (const float*)d_in[20];
    float* out = (float*)d_out;

    // ---- workspace layout ----
    float* ws = (float*)d_ws;
    float* Hb    = ws;                         // N0*H f32
    float* PH    = Hb + (size_t)N0_ * H_;      // (B*K1)*H f32
    float* DINV  = PH + (size_t)B_ * K1_ * H_; // N0
    float* XSP   = DINV + N0_;                 // 4*N0
    int*   CURMAP= (int*)(XSP + 4 * N0_);      // N0
    int*   OFFS  = CURMAP + N0_;               // N0
    int*   OFFE  = OFFS + N0_;                 // N0
    int*   CSRC  = OFFE + N0_;                 // CSRN
    float* COEF  = (float*)(CSRC + CSRN);      // CSRN
    float* Z     = COEF + CSRN;                // B*512
    float* Z1    = Z + B_ * 512;               // B*256
    float* Z2    = Z1 + B_ * 256;              // B*128
    bf16*  AH    = (bf16*)(Z2 + B_ * 128);     // N0*H bf16
    bf16*  AL    = AH + (size_t)N0_ * H_;      // N0*H bf16
    bf16*  WTH   = AL + (size_t)N0_ * H_;      // 3 * 256*256 bf16
    bf16*  WTL   = WTH + 3 * 256 * 256;        // 3 * 256*256 bf16

    init_curmap_k<<<N0_ / 256, 256, 0, stream>>>(CURMAP);

    const int npgs[3]  = { NPG_, K1_, K2_ };
    const int ks[3]    = { K1_, K2_, K3_ };
    const int fis[3]   = { FIN_, H_, H_ };
    const float* Xm[3]  = { x, PH, PH };
    const float* Wm[3]  = { W1, W2, W3 };
    const float* bm[3]  = { b1, b2, b3 };
    const float* Wsm[3] = { Ws1, Ws2, Ws3 };
    const float* bsm[3] = { bs1, bs2, bs3 };

    // convert + transpose + split all three stage weight matrices up front
    for (int st = 0; st < 3; st++)
        wconv_k<<<dim3(fis[st] / 32, H_ / 32), 256, 0, stream>>>(
            Wm[st], WTH + st * 65536, WTL + st * 65536, fis[st], H_);

    for (int st = 0; st < 3; st++) {
        int npg = npgs[st], k = ks[st], FI = fis[st];
        int n = B_ * npg;
        int parts = FI / 64;

        // 1. per-graph padded CSR build from original edges + CURMAP
        csr_build_k<<<B_, 256, 0, stream>>>(esrc, edst, CURMAP, OFFS, OFFE, CSRC, COEF, DINV, npg);

        // 2. AX = Agg(X) — LDS-staged, 64-feature parts; output split bf16 (AH, AL)
        agg_lds_k<<<parts * B_, 512, npg * 64 * 4, stream>>>(
            Xm[st], OFFS, OFFE, CSRC, COEF, DINV, AH, AL, npg, FI, parts);

        // 3. h = relu(AX @ W + b) via split-bf16 MFMA; fused partial xs = h.Ws
        gemm_mfma<<<dim3(n / 64, H_ / 128), 256, 0, stream>>>(
            AH, AL, WTH + st * 65536, WTL + st * 65536, bm[st], Wsm[st],
            Hb, XSP, n, FI, H_);

        // 4-7. score GCN + top-k + pool + readout + CURMAP compose
        score_topk_pool_k<<<B_, 256, 0, stream>>>(Hb, XSP, OFFS, OFFE, CSRC, COEF, DINV, bsm[st],
                                                  CURMAP, PH, Z, npg, k, st > 0 ? 1 : 0);
    }

    // ---- MLP head (f32) ----
    gemm_t<<<dim3(B_ / 64, 256 / 64), 256, 0, stream>>>(Z,  Wl1, bl1, Z1, B_, 512, 256, 1);
    gemm_t<<<dim3(B_ / 64, 128 / 64), 256, 0, stream>>>(Z1, Wl2, bl2, Z2, B_, 256, 128, 1);
    mlp3_lsm_k<<<B_, 64, 0, stream>>>(Z2, Wl3, bl3, out);
}

// Round 10
// 236.291 us; speedup vs baseline: 1.5214x; 1.2139x over previous
//
#include <hip/hip_runtime.h>
#include <hip/hip_bf16.h>
#include <math.h>

typedef __hip_bfloat16 bf16;
typedef __attribute__((ext_vector_type(8))) short bf16x8;
typedef __attribute__((ext_vector_type(4))) float f32x4;

#define B_   256
#define NPG_ 200
#define N0_  (B_*NPG_)     // 51200
#define DEGC 16
#define E_   (N0_*DEGC)    // 819200
#define SLOTG (NPG_*DEGC)  // 3200 edge slots per graph (original layout, never moved)
#define CSTRIDE 4096       // padded CSR slots per graph
#define CSRN (B_*CSTRIDE)
#define FIN_ 128
#define H_   256
#define K1_  100
#define K2_  50
#define K3_  25

// bijective XCD-chunk swizzle (m204)
__device__ __forceinline__ int xcd_swz(int bid, int nwg) {
    int q = nwg >> 3, r = nwg & 7;
    int x = bid & 7, j = bid >> 3;
    return (x < r ? x * (q + 1) : r * (q + 1) + (x - r) * q) + j;
}

__device__ __forceinline__ unsigned short bfu(bf16 h) {
    return *reinterpret_cast<unsigned short*>(&h);
}

// ---- batched W convert: W[K][N] f32 -> WT hi/lo bf16 [N][K], all 3 stages in one launch ----
__global__ void wconv_k(const float* __restrict__ W1, const float* __restrict__ W2,
                        const float* __restrict__ W3, bf16* __restrict__ THb,
                        bf16* __restrict__ TLb) {
    __shared__ float tile[32][33];
    int st = blockIdx.z;
    const float* W = st == 0 ? W1 : (st == 1 ? W2 : W3);
    int K = st == 0 ? 128 : 256;
    int N = 256;
    int k0 = blockIdx.x * 32, n0 = blockIdx.y * 32;
    if (k0 >= K) return;
    bf16* TH = THb + st * 65536;
    bf16* TL = TLb + st * 65536;
    int t = threadIdx.x;
    int tc = t & 31, tr = t >> 5;
    #pragma unroll
    for (int i = 0; i < 4; i++) {
        int kk = tr + i * 8;
        tile[kk][tc] = W[(size_t)(k0 + kk) * N + n0 + tc];
    }
    __syncthreads();
    #pragma unroll
    for (int i = 0; i < 4; i++) {
        int nn = tr + i * 8;
        float v = tile[tc][nn];
        bf16 h = __float2bfloat16(v);
        TH[(size_t)(n0 + nn) * K + k0 + tc] = h;
        TL[(size_t)(n0 + nn) * K + k0 + tc] = __float2bfloat16(v - __bfloat162float(h));
    }
}

// ---- MFMA split-bf16 GEMM: C[M][N] = relu(A@W + bias), fused partial h.Ws dots ----
__global__ __launch_bounds__(256) void gemm_mfma(
        const bf16* __restrict__ AH, const bf16* __restrict__ AL,
        const bf16* __restrict__ BTH, const bf16* __restrict__ BTL,
        const float* __restrict__ bias, const float* __restrict__ Wsd,
        float* __restrict__ C, float* __restrict__ xsp, int M, int K, int N) {
    __shared__ bf16 lAh[64 * 40], lAl[64 * 40];
    __shared__ bf16 lBh[128 * 40], lBl[128 * 40];
    int t = threadIdx.x;
    int w = t >> 6, l = t & 63;
    int wr = w >> 1, wc = w & 1;
    int bm = xcd_swz(blockIdx.x, gridDim.x) * 64;
    int bn = blockIdx.y * 128;
    int srow = t >> 2, skg = (t & 3) * 8;
    f32x4 acc[2][4] = {};
    int coll = l & 15, kg8 = (l >> 4) * 8;
    for (int k0 = 0; k0 < K; k0 += 32) {
        *(uint4*)&lAh[srow * 40 + skg] = *(const uint4*)&AH[(size_t)(bm + srow) * K + k0 + skg];
        *(uint4*)&lAl[srow * 40 + skg] = *(const uint4*)&AL[(size_t)(bm + srow) * K + k0 + skg];
        *(uint4*)&lBh[srow * 40 + skg]        = *(const uint4*)&BTH[(size_t)(bn + srow) * K + k0 + skg];
        *(uint4*)&lBh[(64 + srow) * 40 + skg] = *(const uint4*)&BTH[(size_t)(bn + 64 + srow) * K + k0 + skg];
        *(uint4*)&lBl[srow * 40 + skg]        = *(const uint4*)&BTL[(size_t)(bn + srow) * K + k0 + skg];
        *(uint4*)&lBl[(64 + srow) * 40 + skg] = *(const uint4*)&BTL[(size_t)(bn + 64 + srow) * K + k0 + skg];
        __syncthreads();
        bf16x8 ah[2], al[2], bh[4], bl[4];
        #pragma unroll
        for (int rt = 0; rt < 2; rt++) {
            int row = wr * 32 + rt * 16 + coll;
            ah[rt] = *(const bf16x8*)&lAh[row * 40 + kg8];
            al[rt] = *(const bf16x8*)&lAl[row * 40 + kg8];
        }
        #pragma unroll
        for (int ct = 0; ct < 4; ct++) {
            int col = wc * 64 + ct * 16 + coll;
            bh[ct] = *(const bf16x8*)&lBh[col * 40 + kg8];
            bl[ct] = *(const bf16x8*)&lBl[col * 40 + kg8];
        }
        #pragma unroll
        for (int rt = 0; rt < 2; rt++)
            #pragma unroll
            for (int ct = 0; ct < 4; ct++) {
                acc[rt][ct] = __builtin_amdgcn_mfma_f32_16x16x32_bf16(ah[rt], bh[ct], acc[rt][ct], 0, 0, 0);
                acc[rt][ct] = __builtin_amdgcn_mfma_f32_16x16x32_bf16(ah[rt], bl[ct], acc[rt][ct], 0, 0, 0);
                acc[rt][ct] = __builtin_amdgcn_mfma_f32_16x16x32_bf16(al[rt], bh[ct], acc[rt][ct], 0, 0, 0);
            }
        __syncthreads();
    }
    int gq = l >> 4;
    float bb[4], wv[4];
    #pragma unroll
    for (int ct = 0; ct < 4; ct++) {
        int col = bn + wc * 64 + ct * 16 + coll;
        bb[ct] = bias[col];
        wv[ct] = Wsd ? Wsd[col] : 0.f;
    }
    #pragma unroll
    for (int rt = 0; rt < 2; rt++) {
        int rowb = bm + wr * 32 + rt * 16 + gq * 4;
        float pr[4] = {0.f, 0.f, 0.f, 0.f};
        #pragma unroll
        for (int ct = 0; ct < 4; ct++) {
            int col = bn + wc * 64 + ct * 16 + coll;
            #pragma unroll
            for (int r = 0; r < 4; r++) {
                float v = fmaxf(acc[rt][ct][r] + bb[ct], 0.f);
                C[(size_t)(rowb + r) * N + col] = v;
                pr[r] += v * wv[ct];
            }
        }
        if (Wsd) {
            #pragma unroll
            for (int r = 0; r < 4; r++) {
                pr[r] += __shfl_xor(pr[r], 1); pr[r] += __shfl_xor(pr[r], 2);
                pr[r] += __shfl_xor(pr[r], 4); pr[r] += __shfl_xor(pr[r], 8);
            }
            if (coll == 0) {
                int part = (bn >> 6) + wc;
                #pragma unroll
                for (int r = 0; r < 4; r++)
                    xsp[(size_t)part * N0_ + rowb + r] = pr[r];
            }
        }
    }
}

// -------- per-graph CSR build via CURMAP (edges never rewritten); ident -> curmap==identity --------
__global__ void csr_build_k(const int* __restrict__ esrc, const int* __restrict__ edst,
                            const int* __restrict__ curmap, int* __restrict__ offs,
                            int* __restrict__ offe, int* __restrict__ csrc,
                            float* __restrict__ coef, float* __restrict__ dinv,
                            int npg, int ident) {
    __shared__ int   cml[256];
    __shared__ int   cnt[256];
    __shared__ int   sc[256];
    __shared__ int   pos[256];
    __shared__ float dv[256];
    __shared__ int   ecache[SLOTG];
    int g = xcd_swz(blockIdx.x, B_);
    int t = threadIdx.x;
    int ebase = g * SLOTG;
    int ob0 = g * NPG_;
    int nb0 = g * npg;
    int cbase = g * CSTRIDE;
    cml[t] = (t < NPG_) ? (ident ? ob0 + t : curmap[ob0 + t]) : -1;
    cnt[t] = 0;
    __syncthreads();
    for (int e = t; e < SLOTG; e += 256) {
        int cs = cml[esrc[ebase + e] - ob0];
        int cd = cml[edst[ebase + e] - ob0];
        int pk = -1;
        if (cs >= 0 && cd >= 0) {
            int cs_l = cs - nb0, cd_l = cd - nb0;
            pk = cs_l | (cd_l << 8);
            atomicAdd(&cnt[cd_l], 1);
        }
        ecache[e] = pk;
    }
    __syncthreads();
    int v = (t < npg) ? cnt[t] : 0;
    float dloc = rsqrtf((float)v + 1.0f);
    dv[t] = dloc;
    int vp = (v + 3) & ~3;
    sc[t] = vp; __syncthreads();
    for (int d = 1; d < 256; d <<= 1) {
        int u = (t >= d) ? sc[t - d] : 0;
        __syncthreads();
        sc[t] += u;
        __syncthreads();
    }
    int excl = sc[t] - vp;
    pos[t] = cbase + excl;
    if (t < npg) {
        offs[nb0 + t] = cbase + excl;
        offe[nb0 + t] = cbase + excl + vp;
        dinv[nb0 + t] = dloc;
        for (int p = v; p < vp; p++) {
            csrc[cbase + excl + p] = nb0 + t;
            coef[cbase + excl + p] = 0.0f;
        }
    }
    __syncthreads();
    for (int e = t; e < SLOTG; e += 256) {
        int pk = ecache[e];
        if (pk >= 0) {
            int cs_l = pk & 255, cd_l = pk >> 8;
            int p = atomicAdd(&pos[cd_l], 1);
            csrc[p] = nb0 + cs_l;
            coef[p] = dv[cd_l] * dv[cs_l];
        }
    }
}

// ------- LDS-staged aggregation, float2/lane, prefetched edges; output split bf16 -------
// One block per (graph, 128-feature part). LDS = npg*128 floats (100/50/25 KB).
__global__ __launch_bounds__(1024) void agg_lds_k(
        const float* __restrict__ X, const int* __restrict__ offs,
        const int* __restrict__ offe, const int* __restrict__ csrc,
        const float* __restrict__ coef, const float* __restrict__ dinv,
        bf16* __restrict__ AHo, bf16* __restrict__ ALo, int npg, int FI, int parts) {
    extern __shared__ float lds[];
    int gid = xcd_swz(blockIdx.x, gridDim.x);
    int g = gid / parts, part = gid - g * parts;
    int f0 = part * 128;
    int nb0 = g * npg;
    int t = threadIdx.x;
    int total4 = npg * 32;
    for (int i = t; i < total4; i += 1024) {
        int row = i >> 5, c4 = i & 31;
        ((float4*)lds)[i] = *(const float4*)&X[(size_t)(nb0 + row) * FI + f0 + (c4 << 2)];
    }
    __syncthreads();
    int wid = t >> 6, lane = t & 63;
    const float2* ld2 = (const float2*)lds;     // row stride = 64 float2
    for (int nl = wid; nl < npg; nl += 16) {
        int node = nb0 + nl;
        float dd = dinv[node];
        int e0 = offs[node], e1 = offe[node];
        float ax = 0.f, ay = 0.f;
        int4   s4 = {0, 0, 0, 0};
        float4 c4 = {0.f, 0.f, 0.f, 0.f};
        if (e0 < e1) { s4 = *(const int4*)&csrc[e0]; c4 = *(const float4*)&coef[e0]; }
        for (int j = e0; j < e1; j += 4) {
            int jn = j + 4;
            int4   s4n = {0, 0, 0, 0};
            float4 c4n = {0.f, 0.f, 0.f, 0.f};
            if (jn < e1) { s4n = *(const int4*)&csrc[jn]; c4n = *(const float4*)&coef[jn]; }
            float2 v0 = ld2[(s4.x - nb0) * 64 + lane];
            float2 v1 = ld2[(s4.y - nb0) * 64 + lane];
            float2 v2 = ld2[(s4.z - nb0) * 64 + lane];
            float2 v3 = ld2[(s4.w - nb0) * 64 + lane];
            ax += c4.x * v0.x + c4.y * v1.x + c4.z * v2.x + c4.w * v3.x;
            ay += c4.x * v0.y + c4.y * v1.y + c4.z * v2.y + c4.w * v3.y;
            s4 = s4n; c4 = c4n;
        }
        float2 self = ld2[nl * 64 + lane];
        float s2 = dd * dd;
        ax += s2 * self.x;
        ay += s2 * self.y;
        bf16 hx = __float2bfloat16(ax);
        bf16 hy = __float2bfloat16(ay);
        bf16 lx = __float2bfloat16(ax - __bfloat162float(hx));
        bf16 ly = __float2bfloat16(ay - __bfloat162float(hy));
        size_t idx = (size_t)node * FI + f0 + lane * 2;
        *(unsigned int*)&AHo[idx] = (unsigned int)bfu(hx) | ((unsigned int)bfu(hy) << 16);
        *(unsigned int*)&ALo[idx] = (unsigned int)bfu(lx) | ((unsigned int)bfu(ly) << 16);
    }
}

// -------- fused score GCN + top-k + pool + readout + CURMAP compose --------
__global__ void score_topk_pool_k(const float* __restrict__ h, const float* __restrict__ xsp,
                                  const int* __restrict__ offs, const int* __restrict__ offe,
                                  const int* __restrict__ csrc, const float* __restrict__ coef,
                                  const float* __restrict__ dinv, const float* __restrict__ bs,
                                  int* __restrict__ curmap, float* __restrict__ ph,
                                  float* __restrict__ z, int npg, int k, int accumulate, int ident) {
    __shared__ float xsl[256];
    __shared__ float sc[256];
    __shared__ int   id[256];
    __shared__ int   rl[256];
    __shared__ int   ps[128];
    __shared__ float ts[128];
    int g = xcd_swz(blockIdx.x, B_);
    int t = threadIdx.x;
    int nb0 = g * npg;
    float xv = 0.f;
    if (t < npg) {
        int gi = nb0 + t;
        xv = xsp[gi] + xsp[N0_ + gi] + xsp[2 * N0_ + gi] + xsp[3 * N0_ + gi];
    }
    xsl[t] = xv;
    rl[t] = -1;
    __syncthreads();
    float scv = -INFINITY;
    if (t < npg) {
        int gi = nb0 + t;
        float dd = dinv[gi];
        float acc = 0.f;
        for (int j = offs[gi]; j < offe[gi]; j++)
            acc += coef[j] * xsl[csrc[j] - nb0];
        scv = acc + xsl[t] * dd * dd + bs[0];
    }
    sc[t] = scv;
    id[t] = (t < npg) ? t : 0x7fffffff;
    __syncthreads();
    for (int ksz = 2; ksz <= 256; ksz <<= 1) {
        for (int j = ksz >> 1; j > 0; j >>= 1) {
            int ixj = t ^ j;
            if (ixj > t) {
                float s1 = sc[t], s2 = sc[ixj];
                int i1 = id[t], i2 = id[ixj];
                bool asc = ((t & ksz) == 0);
                bool agtb = (s1 < s2) || (s1 == s2 && i1 > i2);
                if (asc ? agtb : !agtb) { sc[t] = s2; sc[ixj] = s1; id[t] = i2; id[ixj] = i1; }
            }
            __syncthreads();
        }
    }
    if (t < k) {
        rl[id[t]] = g * k + t;
        ps[t] = nb0 + id[t];
        ts[t] = tanhf(sc[t]);
    }
    __syncthreads();
    if (t < NPG_) {
        int o = g * NPG_ + t;
        int old = ident ? o : curmap[o];
        curmap[o] = (old < 0) ? -1 : rl[old - nb0];
    }
    float mx = -INFINITY, sm = 0.f;
    for (int j = 0; j < k; j++) {
        float v = h[(size_t)ps[j] * H_ + t] * ts[j];
        ph[(size_t)(g * k + j) * H_ + t] = v;
        mx = fmaxf(mx, v); sm += v;
    }
    float mean = sm / (float)k;
    if (accumulate) { z[g * 512 + t] += mx; z[g * 512 + 256 + t] += mean; }
    else            { z[g * 512 + t]  = mx; z[g * 512 + 256 + t]  = mean; }
}

// ---------------- fused whole MLP head + log_softmax: one block per batch row ----------------
__global__ __launch_bounds__(256) void mlp_all_k(
        const float* __restrict__ Z, const float* __restrict__ Wl1, const float* __restrict__ bl1,
        const float* __restrict__ Wl2, const float* __restrict__ bl2,
        const float* __restrict__ Wl3, const float* __restrict__ bl3, float* __restrict__ out) {
    __shared__ float zin[512];
    __shared__ float h1[256];
    __shared__ float h2[128];
    int g = blockIdx.x, t = threadIdx.x;
    zin[t]       = Z[g * 512 + t];
    zin[256 + t] = Z[g * 512 + 256 + t];
    __syncthreads();
    float a = bl1[t];
    for (int k = 0; k < 512; k++) a += zin[k] * Wl1[k * 256 + t];
    h1[t] = fmaxf(a, 0.f);
    __syncthreads();
    if (t < 128) {
        float a2 = bl2[t];
        for (int k = 0; k < 256; k++) a2 += h1[k] * Wl2[k * 128 + t];
        h2[t] = fmaxf(a2, 0.f);
    }
    __syncthreads();
    if (t < 64) {
        float a0 = h2[t], a1 = h2[t + 64];
        float r[10];
        #pragma unroll
        for (int n = 0; n < 10; n++) r[n] = a0 * Wl3[t * 10 + n] + a1 * Wl3[(t + 64) * 10 + n];
        #pragma unroll
        for (int d = 1; d < 64; d <<= 1)
            #pragma unroll
            for (int n = 0; n < 10; n++) r[n] += __shfl_xor(r[n], d);
        float v[10]; float mx = -INFINITY;
        #pragma unroll
        for (int n = 0; n < 10; n++) { v[n] = r[n] + bl3[n]; mx = fmaxf(mx, v[n]); }
        float s = 0.f;
        #pragma unroll
        for (int n = 0; n < 10; n++) s += expf(v[n] - mx);
        float ls = logf(s);
        if (t < 10) out[g * 10 + t] = v[t] - mx - ls;
    }
}

extern "C" void kernel_launch(void* const* d_in, const int* in_sizes, int n_in,
                              void* d_out, int out_size, void* d_ws, size_t ws_size,
                              hipStream_t stream) {
    const float* x   = (const float*)d_in[0];
    const int*  esrc = (const int*) d_in[1];
    const int*  edst = (const int*) d_in[2];
    const float *W1 = (const float*)d_in[3],  *b1 = (const float*)d_in[4];
    const float *Ws1= (const float*)d_in[5],  *bs1= (const float*)d_in[6];
    const float *W2 = (const float*)d_in[7],  *b2 = (const float*)d_in[8];
    const float *Ws2= (const float*)d_in[9],  *bs2= (const float*)d_in[10];
    const float *W3 = (const float*)d_in[11], *b3 = (const float*)d_in[12];
    const float *Ws3= (const float*)d_in[13], *bs3= (const float*)d_in[14];
    const float *Wl1= (const float*)d_in[15], *bl1= (const float*)d_in[16];
    const float *Wl2= (const float*)d_in[17], *bl2= (const float*)d_in[18];
    const float *Wl3= (const float*)d_in[19], *bl3= (const float*)d_in[20];
    float* out = (float*)d_out;

    // ---- workspace layout ----
    float* ws = (float*)d_ws;
    float* Hb    = ws;                         // N0*H f32
    float* PH    = Hb + (size_t)N0_ * H_;      // (B*K1)*H f32
    float* DINV  = PH + (size_t)B_ * K1_ * H_; // N0
    float* XSP   = DINV + N0_;                 // 4*N0
    int*   CURMAP= (int*)(XSP + 4 * N0_);      // N0
    int*   OFFS  = CURMAP + N0_;               // N0
    int*   OFFE  = OFFS + N0_;                 // N0
    int*   CSRC  = OFFE + N0_;                 // CSRN
    float* COEF  = (float*)(CSRC + CSRN);      // CSRN
    float* Z     = COEF + CSRN;                // B*512
    bf16*  AH    = (bf16*)(Z + B_ * 512);      // N0*H bf16
    bf16*  AL    = AH + (size_t)N0_ * H_;      // N0*H bf16
    bf16*  WTH   = AL + (size_t)N0_ * H_;      // 3 * 256*256 bf16
    bf16*  WTL   = WTH + 3 * 256 * 256;        // 3 * 256*256 bf16

    const int npgs[3]  = { NPG_, K1_, K2_ };
    const int ks[3]    = { K1_, K2_, K3_ };
    const int fis[3]   = { FIN_, H_, H_ };
    const float* Xm[3]  = { x, PH, PH };
    const float* bm[3]  = { b1, b2, b3 };
    const float* Wsm[3] = { Ws1, Ws2, Ws3 };
    const float* bsm[3] = { bs1, bs2, bs3 };

    // convert + transpose + split all three stage weight matrices (one batched launch)
    wconv_k<<<dim3(8, 8, 3), 256, 0, stream>>>(W1, W2, W3, WTH, WTL);

    for (int st = 0; st < 3; st++) {
        int npg = npgs[st], k = ks[st], FI = fis[st];
        int n = B_ * npg;
        int parts = FI / 128;

        // 1. per-graph padded CSR build (identity curmap at stage 0)
        csr_build_k<<<B_, 256, 0, stream>>>(esrc, edst, CURMAP, OFFS, OFFE, CSRC, COEF, DINV,
                                            npg, st == 0 ? 1 : 0);

        // 2. AX = Agg(X) — LDS-staged, 128-feature parts, float2/lane, prefetched
        agg_lds_k<<<parts * B_, 1024, npg * 128 * 4, stream>>>(
            Xm[st], OFFS, OFFE, CSRC, COEF, DINV, AH, AL, npg, FI, parts);

        // 3. h = relu(AX @ W + b) via split-bf16 MFMA; fused partial xs = h.Ws
        gemm_mfma<<<dim3(n / 64, H_ / 128), 256, 0, stream>>>(
            AH, AL, WTH + st * 65536, WTL + st * 65536, bm[st], Wsm[st],
            Hb, XSP, n, FI, H_);

        // 4-7. score GCN + top-k + pool + readout + CURMAP compose
        score_topk_pool_k<<<B_, 256, 0, stream>>>(Hb, XSP, OFFS, OFFE, CSRC, COEF, DINV, bsm[st],
                                                  CURMAP, PH, Z, npg, k, st > 0 ? 1 : 0,
                                                  st == 0 ? 1 : 0);
    }

    // ---- fused MLP head + log_softmax ----
    mlp_all_k<<<B_, 256, 0, stream>>>(Z, Wl1, bl1, Wl2, bl2, Wl3, bl3, out);
}

// Round 11
// 195.398 us; speedup vs baseline: 1.8398x; 1.2093x over previous
//
#include <hip/hip_runtime.h>
#include <hip/hip_bf16.h>
#include <math.h>

typedef __hip_bfloat16 bf16;
typedef __attribute__((ext_vector_type(8))) short bf16x8;
typedef __attribute__((ext_vector_type(4))) float f32x4;

#define B_   256
#define NPG_ 200
#define N0_  (B_*NPG_)     // 51200
#define DEGC 16
#define E_   (N0_*DEGC)    // 819200
#define SLOTG (NPG_*DEGC)  // 3200 edge slots per graph (original layout, never moved)
#define CSTRIDE 4096       // padded CSR slots per graph
#define CSRN (B_*CSTRIDE)
#define FIN_ 128
#define H_   256
#define K1_  100
#define K2_  50
#define K3_  25

// bijective XCD-chunk swizzle (m204)
__device__ __forceinline__ int xcd_swz(int bid, int nwg) {
    int q = nwg >> 3, r = nwg & 7;
    int x = bid & 7, j = bid >> 3;
    return (x < r ? x * (q + 1) : r * (q + 1) + (x - r) * q) + j;
}

__device__ __forceinline__ unsigned int bfu(bf16 h) {
    return (unsigned int)*reinterpret_cast<unsigned short*>(&h);
}
__device__ __forceinline__ void write_split2(bf16* AH, bf16* AL, size_t idx, float a, float b) {
    bf16 h0 = __float2bfloat16(a), h1 = __float2bfloat16(b);
    bf16 l0 = __float2bfloat16(a - __bfloat162float(h0));
    bf16 l1 = __float2bfloat16(b - __bfloat162float(h1));
    *(unsigned int*)&AH[idx] = bfu(h0) | (bfu(h1) << 16);
    *(unsigned int*)&AL[idx] = bfu(l0) | (bfu(l1) << 16);
}
__device__ __forceinline__ void write_split4(bf16* AH, bf16* AL, size_t idx,
                                             float a, float b, float c, float d) {
    bf16 h0 = __float2bfloat16(a), h1 = __float2bfloat16(b);
    bf16 h2 = __float2bfloat16(c), h3 = __float2bfloat16(d);
    uint2 hh, ll;
    hh.x = bfu(h0) | (bfu(h1) << 16);
    hh.y = bfu(h2) | (bfu(h3) << 16);
    ll.x = bfu(__float2bfloat16(a - __bfloat162float(h0))) |
           (bfu(__float2bfloat16(b - __bfloat162float(h1))) << 16);
    ll.y = bfu(__float2bfloat16(c - __bfloat162float(h2))) |
           (bfu(__float2bfloat16(d - __bfloat162float(h3))) << 16);
    *(uint2*)&AH[idx] = hh;
    *(uint2*)&AL[idx] = ll;
}

// ---- batched W convert: W[K][N] f32 -> WT hi/lo bf16 [N][K], all 3 stages ----
__global__ void wconv_k(const float* __restrict__ W1, const float* __restrict__ W2,
                        const float* __restrict__ W3, bf16* __restrict__ THb,
                        bf16* __restrict__ TLb) {
    __shared__ float tile[32][33];
    int st = blockIdx.z;
    const float* W = st == 0 ? W1 : (st == 1 ? W2 : W3);
    int K = st == 0 ? 128 : 256;
    int N = 256;
    int k0 = blockIdx.x * 32, n0 = blockIdx.y * 32;
    if (k0 >= K) return;
    bf16* TH = THb + st * 65536;
    bf16* TL = TLb + st * 65536;
    int t = threadIdx.x;
    int tc = t & 31, tr = t >> 5;
    #pragma unroll
    for (int i = 0; i < 4; i++) {
        int kk = tr + i * 8;
        tile[kk][tc] = W[(size_t)(k0 + kk) * N + n0 + tc];
    }
    __syncthreads();
    #pragma unroll
    for (int i = 0; i < 4; i++) {
        int nn = tr + i * 8;
        float v = tile[tc][nn];
        bf16 h = __float2bfloat16(v);
        TH[(size_t)(n0 + nn) * K + k0 + tc] = h;
        TL[(size_t)(n0 + nn) * K + k0 + tc] = __float2bfloat16(v - __bfloat162float(h));
    }
}

// ---- MFMA split-bf16 GEMM: C = relu(A@W + bias), fused partial h.Ws dots ----
__global__ __launch_bounds__(256) void gemm_mfma(
        const bf16* __restrict__ AH, const bf16* __restrict__ AL,
        const bf16* __restrict__ BTH, const bf16* __restrict__ BTL,
        const float* __restrict__ bias, const float* __restrict__ Wsd,
        float* __restrict__ C, float* __restrict__ xsp, int M, int K, int N) {
    __shared__ bf16 lAh[64 * 40], lAl[64 * 40];
    __shared__ bf16 lBh[128 * 40], lBl[128 * 40];
    int t = threadIdx.x;
    int w = t >> 6, l = t & 63;
    int wr = w >> 1, wc = w & 1;
    int bm = xcd_swz(blockIdx.x, gridDim.x) * 64;
    int bn = blockIdx.y * 128;
    int srow = t >> 2, skg = (t & 3) * 8;
    f32x4 acc[2][4] = {};
    int coll = l & 15, kg8 = (l >> 4) * 8;
    for (int k0 = 0; k0 < K; k0 += 32) {
        *(uint4*)&lAh[srow * 40 + skg] = *(const uint4*)&AH[(size_t)(bm + srow) * K + k0 + skg];
        *(uint4*)&lAl[srow * 40 + skg] = *(const uint4*)&AL[(size_t)(bm + srow) * K + k0 + skg];
        *(uint4*)&lBh[srow * 40 + skg]        = *(const uint4*)&BTH[(size_t)(bn + srow) * K + k0 + skg];
        *(uint4*)&lBh[(64 + srow) * 40 + skg] = *(const uint4*)&BTH[(size_t)(bn + 64 + srow) * K + k0 + skg];
        *(uint4*)&lBl[srow * 40 + skg]        = *(const uint4*)&BTL[(size_t)(bn + srow) * K + k0 + skg];
        *(uint4*)&lBl[(64 + srow) * 40 + skg] = *(const uint4*)&BTL[(size_t)(bn + 64 + srow) * K + k0 + skg];
        __syncthreads();
        bf16x8 ah[2], al[2], bh[4], bl[4];
        #pragma unroll
        for (int rt = 0; rt < 2; rt++) {
            int row = wr * 32 + rt * 16 + coll;
            ah[rt] = *(const bf16x8*)&lAh[row * 40 + kg8];
            al[rt] = *(const bf16x8*)&lAl[row * 40 + kg8];
        }
        #pragma unroll
        for (int ct = 0; ct < 4; ct++) {
            int col = wc * 64 + ct * 16 + coll;
            bh[ct] = *(const bf16x8*)&lBh[col * 40 + kg8];
            bl[ct] = *(const bf16x8*)&lBl[col * 40 + kg8];
        }
        #pragma unroll
        for (int rt = 0; rt < 2; rt++)
            #pragma unroll
            for (int ct = 0; ct < 4; ct++) {
                acc[rt][ct] = __builtin_amdgcn_mfma_f32_16x16x32_bf16(ah[rt], bh[ct], acc[rt][ct], 0, 0, 0);
                acc[rt][ct] = __builtin_amdgcn_mfma_f32_16x16x32_bf16(ah[rt], bl[ct], acc[rt][ct], 0, 0, 0);
                acc[rt][ct] = __builtin_amdgcn_mfma_f32_16x16x32_bf16(al[rt], bh[ct], acc[rt][ct], 0, 0, 0);
            }
        __syncthreads();
    }
    int gq = l >> 4;
    float bb[4], wv[4];
    #pragma unroll
    for (int ct = 0; ct < 4; ct++) {
        int col = bn + wc * 64 + ct * 16 + coll;
        bb[ct] = bias[col];
        wv[ct] = Wsd[col];
    }
    #pragma unroll
    for (int rt = 0; rt < 2; rt++) {
        int rowb = bm + wr * 32 + rt * 16 + gq * 4;
        float pr[4] = {0.f, 0.f, 0.f, 0.f};
        #pragma unroll
        for (int ct = 0; ct < 4; ct++) {
            int col = bn + wc * 64 + ct * 16 + coll;
            #pragma unroll
            for (int r = 0; r < 4; r++) {
                float v = fmaxf(acc[rt][ct][r] + bb[ct], 0.f);
                C[(size_t)(rowb + r) * N + col] = v;
                pr[r] += v * wv[ct];
            }
        }
        #pragma unroll
        for (int r = 0; r < 4; r++) {
            pr[r] += __shfl_xor(pr[r], 1); pr[r] += __shfl_xor(pr[r], 2);
            pr[r] += __shfl_xor(pr[r], 4); pr[r] += __shfl_xor(pr[r], 8);
        }
        if (coll == 0) {
            int part = (bn >> 6) + wc;
            #pragma unroll
            for (int r = 0; r < 4; r++)
                xsp[(size_t)part * N0_ + rowb + r] = pr[r];
        }
    }
}

// ---- stage 0: fused CSR build + aggregation (one block per graph, 1024 thr) ----
// offs/offe/dinv indexed [g*256 + local] (stride-256, block-local across stages).
__global__ __launch_bounds__(1024) void csr_agg0_k(
        const float* __restrict__ X, const int* __restrict__ esrc, const int* __restrict__ edst,
        int* __restrict__ offs, int* __restrict__ offe, int* __restrict__ csrc,
        float* __restrict__ coef, float* __restrict__ dinv,
        bf16* __restrict__ AHo, bf16* __restrict__ ALo) {
    extern __shared__ float lds[];
    float* xs   = lds;                       // 200*128
    int* ecache = (int*)(xs + NPG_ * 128);   // SLOTG
    int* cnt    = ecache + SLOTG;
    int* scn    = cnt + 256;
    int* pos    = scn + 256;
    float* dv   = (float*)(pos + 256);
    int g = xcd_swz(blockIdx.x, B_);
    int t = threadIdx.x;
    int ebase = g * SLOTG, nb0 = g * NPG_, obase = g * 256, cbase = g * CSTRIDE;
    if (t < 256) cnt[t] = 0;
    __syncthreads();
    for (int i = t; i < NPG_ * 32; i += 1024) {      // X slice: 200 rows x 32 float4
        int row = i >> 5, c4 = i & 31;
        ((float4*)xs)[i] = *(const float4*)&X[(size_t)(nb0 + row) * FIN_ + (c4 << 2)];
    }
    for (int e = t; e < SLOTG; e += 1024) {
        int cs_l = esrc[ebase + e] - nb0;
        int cd_l = edst[ebase + e] - nb0;
        ecache[e] = cs_l | (cd_l << 8);
        atomicAdd(&cnt[cd_l], 1);
    }
    __syncthreads();
    int v = 0, vp = 0;
    if (t < 256) {
        v = (t < NPG_) ? cnt[t] : 0;
        dv[t] = rsqrtf((float)v + 1.0f);
        vp = (v + 3) & ~3;
        scn[t] = vp;
    }
    __syncthreads();
    for (int d = 1; d < 256; d <<= 1) {
        int u = (t < 256 && t >= d) ? scn[t - d] : 0;
        __syncthreads();
        if (t < 256) scn[t] += u;
        __syncthreads();
    }
    if (t < 256) {
        int excl = scn[t] - vp;
        pos[t] = cbase + excl;
        if (t < NPG_) {
            offs[obase + t] = cbase + excl;
            offe[obase + t] = cbase + excl + vp;
            dinv[obase + t] = dv[t];
            for (int p = v; p < vp; p++) { csrc[cbase + excl + p] = nb0 + t; coef[cbase + excl + p] = 0.f; }
        }
    }
    __syncthreads();
    for (int e = t; e < SLOTG; e += 1024) {
        int pk = ecache[e];
        int cs_l = pk & 255, cd_l = pk >> 8;
        int p = atomicAdd(&pos[cd_l], 1);
        csrc[p] = nb0 + cs_l;
        coef[p] = dv[cd_l] * dv[cs_l];
    }
    __syncthreads();
    int wid = t >> 6, lane = t & 63;
    const float2* ld2 = (const float2*)xs;      // row stride 64 float2
    for (int nl = wid; nl < NPG_; nl += 16) {
        int node = nb0 + nl;
        float dd = dv[nl];
        int e0 = offs[obase + nl], e1 = offe[obase + nl];
        float ax = 0.f, ay = 0.f;
        for (int j = e0; j < e1; j += 4) {
            int4   s4 = *(const int4*)&csrc[j];
            float4 c4 = *(const float4*)&coef[j];
            float2 v0 = ld2[(s4.x - nb0) * 64 + lane];
            float2 v1 = ld2[(s4.y - nb0) * 64 + lane];
            float2 v2 = ld2[(s4.z - nb0) * 64 + lane];
            float2 v3 = ld2[(s4.w - nb0) * 64 + lane];
            ax += c4.x * v0.x + c4.y * v1.x + c4.z * v2.x + c4.w * v3.x;
            ay += c4.x * v0.y + c4.y * v1.y + c4.z * v2.y + c4.w * v3.y;
        }
        float2 self = ld2[nl * 64 + lane];
        float s2 = dd * dd;
        ax += s2 * self.x; ay += s2 * self.y;
        write_split2(AHo, ALo, (size_t)node * FIN_ + lane * 2, ax, ay);
    }
}

// ---- fused: score+topk+pool+readout(stage s) THEN csr+agg(stage s+1) ----
__global__ __launch_bounds__(1024) void stp_csr_agg_k(
        const float* __restrict__ Hb, const float* __restrict__ xsp,
        int* __restrict__ offs, int* __restrict__ offe, int* __restrict__ csrc,
        float* __restrict__ coef, float* __restrict__ dinv, const float* __restrict__ bs,
        const int* __restrict__ esrc, const int* __restrict__ edst,
        int* __restrict__ curmap, float* __restrict__ z,
        bf16* __restrict__ AHo, bf16* __restrict__ ALo,
        int npgA, int kA, int accumulate, int identCur) {
    extern __shared__ float lds[];
    float* xs   = lds;                        // kA*256 (pooled features)
    int* ecache = (int*)(xs + kA * 256);      // SLOTG
    int* cml    = ecache + SLOTG;             // 256
    int* cnt    = cml + 256;
    int* scn    = cnt + 256;
    int* pos    = scn + 256;
    float* dv   = (float*)(pos + 256);
    float* xsl  = dv + 256;
    float* sco  = xsl + 256;
    int* idx    = (int*)(sco + 256);
    int* rl     = idx + 256;
    int* ps     = rl + 256;                   // 128
    float* ts   = (float*)(ps + 128);         // 128
    float* pred = ts + 128;                   // 2048
    int g = xcd_swz(blockIdx.x, B_);
    int t = threadIdx.x;
    int nb0 = g * npgA, ob0 = g * NPG_, obase = g * 256;
    // ---- phase A: score GCN ----
    if (t < 256) {
        float xv = 0.f;
        if (t < npgA) {
            int gi = nb0 + t;
            xv = xsp[gi] + xsp[N0_ + gi] + xsp[2 * N0_ + gi] + xsp[3 * N0_ + gi];
        }
        xsl[t] = xv;
        rl[t] = -1;
        cnt[t] = 0;
    }
    __syncthreads();
    if (t < 256) {
        float scv = -INFINITY;
        if (t < npgA) {
            float dd = dinv[obase + t];
            float acc = 0.f;
            for (int j = offs[obase + t]; j < offe[obase + t]; j++)
                acc += coef[j] * xsl[csrc[j] - nb0];
            scv = acc + xsl[t] * dd * dd + bs[0];
        }
        sco[t] = scv;
        idx[t] = (t < npgA) ? t : 0x7fffffff;
    }
    __syncthreads();
    // ---- bitonic top-k ----
    for (int ksz = 2; ksz <= 256; ksz <<= 1) {
        for (int j = ksz >> 1; j > 0; j >>= 1) {
            int ixj = t ^ j;
            if (t < 256 && ixj > t) {
                float s1 = sco[t], s2 = sco[ixj];
                int i1 = idx[t], i2 = idx[ixj];
                bool asc = ((t & ksz) == 0);
                bool agtb = (s1 < s2) || (s1 == s2 && i1 > i2);
                if (asc ? agtb : !agtb) { sco[t] = s2; sco[ixj] = s1; idx[t] = i2; idx[ixj] = i1; }
            }
            __syncthreads();
        }
    }
    if (t < kA) {
        rl[idx[t]] = g * kA + t;
        ps[t] = nb0 + idx[t];
        ts[t] = tanhf(sco[t]);
    }
    __syncthreads();
    // ---- pool into LDS + partial readout (all 1024 threads) ----
    {
        int f = t & 255, grp = t >> 8;
        float mx = -INFINITY, sm = 0.f;
        for (int j = grp; j < kA; j += 4) {
            float v = Hb[(size_t)ps[j] * H_ + f] * ts[j];
            xs[j * 256 + f] = v;
            mx = fmaxf(mx, v); sm += v;
        }
        pred[grp * 256 + f] = mx;
        pred[1024 + grp * 256 + f] = sm;
    }
    __syncthreads();
    // ---- readout reduce + curmap compose ----
    if (t < 256) {
        float mx = fmaxf(fmaxf(pred[t], pred[256 + t]), fmaxf(pred[512 + t], pred[768 + t]));
        float sm = pred[1024 + t] + pred[1280 + t] + pred[1536 + t] + pred[1792 + t];
        float mean = sm / (float)kA;
        if (accumulate) { z[g * 512 + t] += mx; z[g * 512 + 256 + t] += mean; }
        else            { z[g * 512 + t]  = mx; z[g * 512 + 256 + t]  = mean; }
        int nl = -1;
        if (t < NPG_) {
            int oldl;
            if (identCur) oldl = t;
            else { int gc = curmap[ob0 + t]; oldl = (gc < 0) ? -1 : gc - nb0; }
            nl = (oldl < 0) ? -1 : rl[oldl];
            curmap[ob0 + t] = nl;
        }
        cml[t] = nl;
    }
    __syncthreads();
    // ---- phase B: CSR build for new stage (npg_new = kA) ----
    int nb0n = g * kA, cbase = g * CSTRIDE;
    for (int e = t; e < SLOTG; e += 1024) {
        int cs = cml[esrc[g * SLOTG + e] - ob0];
        int cd = cml[edst[g * SLOTG + e] - ob0];
        int pk = -1;
        if (cs >= 0 && cd >= 0) {
            int cs_l = cs - nb0n, cd_l = cd - nb0n;
            pk = cs_l | (cd_l << 8);
            atomicAdd(&cnt[cd_l], 1);
        }
        ecache[e] = pk;
    }
    __syncthreads();
    int v = 0, vp = 0;
    if (t < 256) {
        v = (t < kA) ? cnt[t] : 0;
        dv[t] = rsqrtf((float)v + 1.0f);
        vp = (v + 3) & ~3;
        scn[t] = vp;
    }
    __syncthreads();
    for (int d = 1; d < 256; d <<= 1) {
        int u = (t < 256 && t >= d) ? scn[t - d] : 0;
        __syncthreads();
        if (t < 256) scn[t] += u;
        __syncthreads();
    }
    if (t < 256) {
        int excl = scn[t] - vp;
        pos[t] = cbase + excl;
        if (t < kA) {
            offs[obase + t] = cbase + excl;
            offe[obase + t] = cbase + excl + vp;
            dinv[obase + t] = dv[t];
            for (int p = v; p < vp; p++) { csrc[cbase + excl + p] = nb0n + t; coef[cbase + excl + p] = 0.f; }
        }
    }
    __syncthreads();
    for (int e = t; e < SLOTG; e += 1024) {
        int pk = ecache[e];
        if (pk >= 0) {
            int cs_l = pk & 255, cd_l = pk >> 8;
            int p = atomicAdd(&pos[cd_l], 1);
            csrc[p] = nb0n + cs_l;
            coef[p] = dv[cd_l] * dv[cs_l];
        }
    }
    __syncthreads();
    // ---- phase C: aggregation of pooled features (FI = 256) ----
    int wid = t >> 6, lane = t & 63;
    const float4* ld4 = (const float4*)xs;      // row stride 64 float4
    for (int nl2 = wid; nl2 < kA; nl2 += 16) {
        int node = nb0n + nl2;
        float dd = dv[nl2];
        int e0 = offs[obase + nl2], e1 = offe[obase + nl2];
        float ax = 0.f, ay = 0.f, az = 0.f, aw = 0.f;
        for (int j = e0; j < e1; j += 4) {
            int4   s4 = *(const int4*)&csrc[j];
            float4 c4 = *(const float4*)&coef[j];
            float4 v0 = ld4[(s4.x - nb0n) * 64 + lane];
            float4 v1 = ld4[(s4.y - nb0n) * 64 + lane];
            float4 v2 = ld4[(s4.z - nb0n) * 64 + lane];
            float4 v3 = ld4[(s4.w - nb0n) * 64 + lane];
            ax += c4.x * v0.x + c4.y * v1.x + c4.z * v2.x + c4.w * v3.x;
            ay += c4.x * v0.y + c4.y * v1.y + c4.z * v2.y + c4.w * v3.y;
            az += c4.x * v0.z + c4.y * v1.z + c4.z * v2.z + c4.w * v3.z;
            aw += c4.x * v0.w + c4.y * v1.w + c4.z * v2.w + c4.w * v3.w;
        }
        float4 self = ld4[nl2 * 64 + lane];
        float s2 = dd * dd;
        ax += s2 * self.x; ay += s2 * self.y; az += s2 * self.z; aw += s2 * self.w;
        write_split4(AHo, ALo, (size_t)node * H_ + lane * 4, ax, ay, az, aw);
    }
}

// ---- final stage tail: score + topk + readout only ----
__global__ void stp_final_k(const float* __restrict__ Hb, const float* __restrict__ xsp,
                            const int* __restrict__ offs, const int* __restrict__ offe,
                            const int* __restrict__ csrc, const float* __restrict__ coef,
                            const float* __restrict__ dinv, const float* __restrict__ bs,
                            float* __restrict__ z, int npgA, int kA) {
    __shared__ float xsl[256];
    __shared__ float sco[256];
    __shared__ int   idx[256];
    __shared__ int   ps[128];
    __shared__ float ts[128];
    int g = xcd_swz(blockIdx.x, B_);
    int t = threadIdx.x;
    int nb0 = g * npgA, obase = g * 256;
    float xv = 0.f;
    if (t < npgA) {
        int gi = nb0 + t;
        xv = xsp[gi] + xsp[N0_ + gi] + xsp[2 * N0_ + gi] + xsp[3 * N0_ + gi];
    }
    xsl[t] = xv;
    __syncthreads();
    float scv = -INFINITY;
    if (t < npgA) {
        float dd = dinv[obase + t];
        float acc = 0.f;
        for (int j = offs[obase + t]; j < offe[obase + t]; j++)
            acc += coef[j] * xsl[csrc[j] - nb0];
        scv = acc + xsl[t] * dd * dd + bs[0];
    }
    sco[t] = scv;
    idx[t] = (t < npgA) ? t : 0x7fffffff;
    __syncthreads();
    for (int ksz = 2; ksz <= 256; ksz <<= 1) {
        for (int j = ksz >> 1; j > 0; j >>= 1) {
            int ixj = t ^ j;
            if (ixj > t) {
                float s1 = sco[t], s2 = sco[ixj];
                int i1 = idx[t], i2 = idx[ixj];
                bool asc = ((t & ksz) == 0);
                bool agtb = (s1 < s2) || (s1 == s2 && i1 > i2);
                if (asc ? agtb : !agtb) { sco[t] = s2; sco[ixj] = s1; idx[t] = i2; idx[ixj] = i1; }
            }
            __syncthreads();
        }
    }
    if (t < kA) { ps[t] = nb0 + idx[t]; ts[t] = tanhf(sco[t]); }
    __syncthreads();
    float mx = -INFINITY, sm = 0.f;
    for (int j = 0; j < kA; j++) {
        float v = Hb[(size_t)ps[j] * H_ + t] * ts[j];
        mx = fmaxf(mx, v); sm += v;
    }
    z[g * 512 + t] += mx;
    z[g * 512 + 256 + t] += sm / (float)kA;
}

// ---------------- fused whole MLP head + log_softmax ----------------
__global__ __launch_bounds__(256) void mlp_all_k(
        const float* __restrict__ Z, const float* __restrict__ Wl1, const float* __restrict__ bl1,
        const float* __restrict__ Wl2, const float* __restrict__ bl2,
        const float* __restrict__ Wl3, const float* __restrict__ bl3, float* __restrict__ out) {
    __shared__ float zin[512];
    __shared__ float h1[256];
    __shared__ float h2[128];
    int g = blockIdx.x, t = threadIdx.x;
    zin[t]       = Z[g * 512 + t];
    zin[256 + t] = Z[g * 512 + 256 + t];
    __syncthreads();
    float a = bl1[t];
    for (int k = 0; k < 512; k++) a += zin[k] * Wl1[k * 256 + t];
    h1[t] = fmaxf(a, 0.f);
    __syncthreads();
    if (t < 128) {
        float a2 = bl2[t];
        for (int k = 0; k < 256; k++) a2 += h1[k] * Wl2[k * 128 + t];
        h2[t] = fmaxf(a2, 0.f);
    }
    __syncthreads();
    if (t < 64) {
        float a0 = h2[t], a1 = h2[t + 64];
        float r[10];
        #pragma unroll
        for (int n = 0; n < 10; n++) r[n] = a0 * Wl3[t * 10 + n] + a1 * Wl3[(t + 64) * 10 + n];
        #pragma unroll
        for (int d = 1; d < 64; d <<= 1)
            #pragma unroll
            for (int n = 0; n < 10; n++) r[n] += __shfl_xor(r[n], d);
        float v[10]; float mx = -INFINITY;
        #pragma unroll
        for (int n = 0; n < 10; n++) { v[n] = r[n] + bl3[n]; mx = fmaxf(mx, v[n]); }
        float s = 0.f;
        #pragma unroll
        for (int n = 0; n < 10; n++) s += expf(v[n] - mx);
        float ls = logf(s);
        if (t < 10) out[g * 10 + t] = v[t] - mx - ls;
    }
}

extern "C" void kernel_launch(void* const* d_in, const int* in_sizes, int n_in,
                              void* d_out, int out_size, void* d_ws, size_t ws_size,
                              hipStream_t stream) {
    const float* x   = (const float*)d_in[0];
    const int*  esrc = (const int*) d_in[1];
    const int*  edst = (const int*) d_in[2];
    const float *W1 = (const float*)d_in[3],  *b1 = (const float*)d_in[4];
    const float *Ws1= (const float*)d_in[5],  *bs1= (const float*)d_in[6];
    const float *W2 = (const float*)d_in[7],  *b2 = (const float*)d_in[8];
    const float *Ws2= (const float*)d_in[9],  *bs2= (const float*)d_in[10];
    const float *W3 = (const float*)d_in[11], *b3 = (const float*)d_in[12];
    const float *Ws3= (const float*)d_in[13], *bs3= (const float*)d_in[14];
    const float *Wl1= (const float*)d_in[15], *bl1= (const float*)d_in[16];
    const float *Wl2= (const float*)d_in[17], *bl2= (const float*)d_in[18];
    const float *Wl3= (const float*)d_in[19], *bl3= (const float*)d_in[20];
    float* out = (float*)d_out;

    // ---- workspace layout ----
    float* ws = (float*)d_ws;
    float* Hb    = ws;                         // N0*H f32
    float* XSP   = Hb + (size_t)N0_ * H_;      // 4*N0
    int*   OFFS  = (int*)(XSP + 4 * N0_);      // B*256
    int*   OFFE  = OFFS + B_ * 256;            // B*256
    float* DINV  = (float*)(OFFE + B_ * 256);  // B*256
    int*   CURMAP= (int*)(DINV + B_ * 256);    // N0
    int*   CSRC  = CURMAP + N0_;               // CSRN
    float* COEF  = (float*)(CSRC + CSRN);      // CSRN
    float* Z     = COEF + CSRN;                // B*512
    bf16*  AH    = (bf16*)(Z + B_ * 512);      // N0*H bf16
    bf16*  AL    = AH + (size_t)N0_ * H_;      // N0*H bf16
    bf16*  WTH   = AL + (size_t)N0_ * H_;      // 3 * 256*256 bf16
    bf16*  WTL   = WTH + 3 * 256 * 256;        // 3 * 256*256 bf16

    // 1. weight convert (all 3 stages)
    wconv_k<<<dim3(8, 8, 3), 256, 0, stream>>>(W1, W2, W3, WTH, WTL);

    // 2. stage-0 CSR + aggregation fused
    size_t lds0 = (size_t)(NPG_ * 128 + SLOTG + 4 * 256) * 4;
    csr_agg0_k<<<B_, 1024, lds0, stream>>>(x, esrc, edst, OFFS, OFFE, CSRC, COEF, DINV, AH, AL);

    // 3. gemm stage 0 (K=128)
    gemm_mfma<<<dim3(N0_ / 64, 2), 256, 0, stream>>>(
        AH, AL, WTH, WTL, b1, Ws1, Hb, XSP, N0_, FIN_, H_);

    // 4. stp(stage0) + csr+agg(stage1) fused
    size_t lds1 = (size_t)(K1_ * 256 + SLOTG + 5 * 256 + 4 * 256 + 2 * 128 + 2048) * 4;
    stp_csr_agg_k<<<B_, 1024, lds1, stream>>>(
        Hb, XSP, OFFS, OFFE, CSRC, COEF, DINV, bs1, esrc, edst, CURMAP, Z, AH, AL,
        NPG_, K1_, 0, 1);

    // 5. gemm stage 1 (K=256)
    gemm_mfma<<<dim3(B_ * K1_ / 64, 2), 256, 0, stream>>>(
        AH, AL, WTH + 65536, WTL + 65536, b2, Ws2, Hb, XSP, B_ * K1_, H_, H_);

    // 6. stp(stage1) + csr+agg(stage2) fused
    size_t lds2 = (size_t)(K2_ * 256 + SLOTG + 5 * 256 + 4 * 256 + 2 * 128 + 2048) * 4;
    stp_csr_agg_k<<<B_, 1024, lds2, stream>>>(
        Hb, XSP, OFFS, OFFE, CSRC, COEF, DINV, bs2, esrc, edst, CURMAP, Z, AH, AL,
        K1_, K2_, 1, 0);

    // 7. gemm stage 2 (K=256)
    gemm_mfma<<<dim3(B_ * K2_ / 64, 2), 256, 0, stream>>>(
        AH, AL, WTH + 2 * 65536, WTL + 2 * 65536, b3, Ws3, Hb, XSP, B_ * K2_, H_, H_);

    // 8. final score + topk + readout
    stp_final_k<<<B_, 256, 0, stream>>>(Hb, XSP, OFFS, OFFE, CSRC, COEF, DINV, bs3, Z, K2_, K3_);

    // 9. MLP head + log_softmax
    mlp_all_k<<<B_, 256, 0, stream>>>(Z, Wl1, bl1, Wl2, bl2, Wl3, bl3, out);
}